// Round 4
// baseline (414.259 us; speedup 1.0000x reference)
//
#include <hip/hip_runtime.h>
#include <hip/hip_bf16.h>
#include <stdint.h>

#define DIM 512
#define NROWS 1024
#define NCLS 70722
#define BK 32
#define NCTILE 553     // ceil(70722/128)

typedef float  floatx4 __attribute__((ext_vector_type(4)));
typedef short  shortx8 __attribute__((ext_vector_type(8)));

__device__ __forceinline__ unsigned short f2bf(float f) {
    union { float f; unsigned int u; } v; v.f = f;
    unsigned int r = v.u + 0x7FFFu + ((v.u >> 16) & 1u);  // RNE
    return (unsigned short)(r >> 16);
}

__device__ __forceinline__ float wave_reduce_sum(float s) {
    #pragma unroll
    for (int m = 1; m < 64; m <<= 1) s += __shfl_xor(s, m);
    return s;
}

// --- kernel 1: per-row x norms + normalized bf16 x + rowsum zero -----------
__global__ __launch_bounds__(256) void prep_x_kernel(
        const float* __restrict__ x, unsigned short* __restrict__ normx,
        float* __restrict__ rownorm, float* __restrict__ rowsum) {
    int wv = threadIdx.x >> 6, lane = threadIdx.x & 63;
    if (threadIdx.x < 4) rowsum[blockIdx.x * 4 + threadIdx.x] = 0.0f;
    int row = blockIdx.x * 4 + wv;
    const float4* src = (const float4*)(x + row * DIM);
    float4 a = src[lane], b = src[lane + 64];
    float ss = a.x*a.x + a.y*a.y + a.z*a.z + a.w*a.w
             + b.x*b.x + b.y*b.y + b.z*b.z + b.w*b.w;
    ss = wave_reduce_sum(ss);
    float norm = sqrtf(ss);
    float inv  = 1.0f / fmaxf(norm, 1e-12f);
    ushort4 o0; o0.x = f2bf(a.x*inv); o0.y = f2bf(a.y*inv); o0.z = f2bf(a.z*inv); o0.w = f2bf(a.w*inv);
    ushort4 o1; o1.x = f2bf(b.x*inv); o1.y = f2bf(b.y*inv); o1.z = f2bf(b.z*inv); o1.w = f2bf(b.w*inv);
    ((ushort4*)(normx + row * DIM))[lane]      = o0;
    ((ushort4*)(normx + row * DIM))[lane + 64] = o1;
    if (lane == 0) rownorm[row] = norm;
}

// --- kernel 2: self-contained fp32 cosine of the label column --------------
__global__ __launch_bounds__(256) void coslab_kernel(
        const float* __restrict__ x, const float* __restrict__ W,
        const int* __restrict__ labels, float* __restrict__ coslab) {
    int wv = threadIdx.x >> 6, lane = threadIdx.x & 63;
    int r = blockIdx.x * 4 + wv;
    int lab = labels[r];
    const float4* xs = (const float4*)(x + r * DIM);
    const float4* ws = (const float4*)(W + (size_t)lab * DIM);
    float4 xa = xs[lane], xb = xs[lane + 64];
    float4 wa = ws[lane], wb = ws[lane + 64];
    float dxx = xa.x*xa.x + xa.y*xa.y + xa.z*xa.z + xa.w*xa.w
              + xb.x*xb.x + xb.y*xb.y + xb.z*xb.z + xb.w*xb.w;
    float dww = wa.x*wa.x + wa.y*wa.y + wa.z*wa.z + wa.w*wa.w
              + wb.x*wb.x + wb.y*wb.y + wb.z*wb.z + wb.w*wb.w;
    float dxw = xa.x*wa.x + xa.y*wa.y + xa.z*wa.z + xa.w*wa.w
              + xb.x*wb.x + xb.y*wb.y + xb.z*wb.z + xb.w*wb.w;
    dxx = wave_reduce_sum(dxx);
    dww = wave_reduce_sum(dww);
    dxw = wave_reduce_sum(dxw);
    if (lane == 0)
        coslab[r] = dxw / (fmaxf(sqrtf(dxx), 1e-12f) * fmaxf(sqrtf(dww), 1e-12f));
}

// --- kernel 3: fused GEMM: fp32-W in-loop convert + norm + sumexp ----------
// A fragments direct from global (normx is L2-resident); B staged fp32->bf16
// into XOR-swizzled LDS; per-class sum(w^2) accumulated during staging and
// applied as rsqrt in the epilogue. XCD swizzle: 8 mtile-blocks of a ctile
// share blockIdx%8 -> same XCD -> fp32 W tile fetched ~once from HBM.
__global__ __launch_bounds__(256) void gemm3_kernel(
        const unsigned short* __restrict__ normx, const float* __restrict__ W,
        float* __restrict__ rowsum) {
    __shared__ unsigned short Bs[128 * BK];   // swizzled: row*32 + (chunk^s(row))*8
    __shared__ float invs[128];
    __shared__ float red[128];
    int b = blockIdx.x;
    int ctile = (b >> 6) * 8 + (b & 7);
    int mtile = (b >> 3) & 7;
    if (ctile >= NCTILE) return;              // whole block exits together
    int t = threadIdx.x, lane = t & 63, wv = t >> 6;
    if (t < 128) red[t] = 0.0f;

    // B staging map: thread t covers rows r0 and 64+r0, k-chunk kq (8 floats)
    int r0 = t >> 2;
    int kq = t & 3;
    int cls0 = min(ctile * 128 + r0,      NCLS - 1);
    int cls1 = min(ctile * 128 + 64 + r0, NCLS - 1);
    const float* w0 = W + (size_t)cls0 * DIM + kq * 8;
    const float* w1 = W + (size_t)cls1 * DIM + kq * 8;
    int slot = kq ^ ((r0 ^ (r0 >> 2)) & 3);   // s(row) uses row's low 4 bits only
    unsigned short* bd0 = Bs + r0 * BK + slot * 8;
    unsigned short* bd1 = Bs + (64 + r0) * BK + slot * 8;

    // fragment map
    int wm = (wv >> 1) * 64, wn = (wv & 1) * 64;
    int fr = lane & 15, fq = lane >> 4;
    const unsigned short* aBase =
        normx + (size_t)(mtile * 128 + wm + fr) * DIM + fq * 8;

    floatx4 acc[4][4] = {};
    float sq0 = 0.0f, sq1 = 0.0f;

    // W reg double-buffer: setX for even phases, setY for odd
    float4 xA0 = *(const float4*)(w0);
    float4 xA1 = *(const float4*)(w0 + 4);
    float4 xB0 = *(const float4*)(w1);
    float4 xB1 = *(const float4*)(w1 + 4);
    float4 yA0, yA1, yB0, yB1;

    #pragma unroll 1
    for (int kc = 0; kc < DIM; kc += 2 * BK) {
        // ===== phase A: k = kc, uses setX =====
        sq0 += xA0.x*xA0.x + xA0.y*xA0.y + xA0.z*xA0.z + xA0.w*xA0.w
             + xA1.x*xA1.x + xA1.y*xA1.y + xA1.z*xA1.z + xA1.w*xA1.w;
        sq1 += xB0.x*xB0.x + xB0.y*xB0.y + xB0.z*xB0.z + xB0.w*xB0.w
             + xB1.x*xB1.x + xB1.y*xB1.y + xB1.z*xB1.z + xB1.w*xB1.w;
        __syncthreads();   // prior-phase fragment reads done
        {
            union { unsigned short u[8]; uint4 v; } p0, p1;
            p0.u[0]=f2bf(xA0.x); p0.u[1]=f2bf(xA0.y); p0.u[2]=f2bf(xA0.z); p0.u[3]=f2bf(xA0.w);
            p0.u[4]=f2bf(xA1.x); p0.u[5]=f2bf(xA1.y); p0.u[6]=f2bf(xA1.z); p0.u[7]=f2bf(xA1.w);
            p1.u[0]=f2bf(xB0.x); p1.u[1]=f2bf(xB0.y); p1.u[2]=f2bf(xB0.z); p1.u[3]=f2bf(xB0.w);
            p1.u[4]=f2bf(xB1.x); p1.u[5]=f2bf(xB1.y); p1.u[6]=f2bf(xB1.z); p1.u[7]=f2bf(xB1.w);
            *(uint4*)bd0 = p0.v;
            *(uint4*)bd1 = p1.v;
        }
        __syncthreads();   // LDS ready
        // prefetch W for phase B (global->VGPR; one full phase of slack)
        yA0 = *(const float4*)(w0 + kc + BK);
        yA1 = *(const float4*)(w0 + kc + BK + 4);
        yB0 = *(const float4*)(w1 + kc + BK);
        yB1 = *(const float4*)(w1 + kc + BK + 4);
        {
            shortx8 af[4], bfr[4];
            #pragma unroll
            for (int mt = 0; mt < 4; ++mt)
                af[mt] = *(const shortx8*)(aBase + mt * 16 * DIM + kc);
            #pragma unroll
            for (int nt = 0; nt < 4; ++nt) {
                int R = wn + nt * 16 + fr;
                bfr[nt] = *(const shortx8*)(Bs + R * BK + ((fq ^ ((R ^ (R >> 2)) & 3)) * 8));
            }
            #pragma unroll
            for (int mt = 0; mt < 4; ++mt)
                #pragma unroll
                for (int nt = 0; nt < 4; ++nt)
                    acc[mt][nt] = __builtin_amdgcn_mfma_f32_16x16x32_bf16(
                        af[mt], bfr[nt], acc[mt][nt], 0, 0, 0);
        }

        // ===== phase B: k = kc+BK, uses setY =====
        sq0 += yA0.x*yA0.x + yA0.y*yA0.y + yA0.z*yA0.z + yA0.w*yA0.w
             + yA1.x*yA1.x + yA1.y*yA1.y + yA1.z*yA1.z + yA1.w*yA1.w;
        sq1 += yB0.x*yB0.x + yB0.y*yB0.y + yB0.z*yB0.z + yB0.w*yB0.w
             + yB1.x*yB1.x + yB1.y*yB1.y + yB1.z*yB1.z + yB1.w*yB1.w;
        __syncthreads();
        {
            union { unsigned short u[8]; uint4 v; } p0, p1;
            p0.u[0]=f2bf(yA0.x); p0.u[1]=f2bf(yA0.y); p0.u[2]=f2bf(yA0.z); p0.u[3]=f2bf(yA0.w);
            p0.u[4]=f2bf(yA1.x); p0.u[5]=f2bf(yA1.y); p0.u[6]=f2bf(yA1.z); p0.u[7]=f2bf(yA1.w);
            p1.u[0]=f2bf(yB0.x); p1.u[1]=f2bf(yB0.y); p1.u[2]=f2bf(yB0.z); p1.u[3]=f2bf(yB0.w);
            p1.u[4]=f2bf(yB1.x); p1.u[5]=f2bf(yB1.y); p1.u[6]=f2bf(yB1.z); p1.u[7]=f2bf(yB1.w);
            *(uint4*)bd0 = p0.v;
            *(uint4*)bd1 = p1.v;
        }
        __syncthreads();
        // prefetch W for next phase A (wraps harmlessly on last iter)
        {
            int kn = (kc + 2 * BK) & (DIM - 1);
            xA0 = *(const float4*)(w0 + kn);
            xA1 = *(const float4*)(w0 + kn + 4);
            xB0 = *(const float4*)(w1 + kn);
            xB1 = *(const float4*)(w1 + kn + 4);
        }
        {
            shortx8 af[4], bfr[4];
            #pragma unroll
            for (int mt = 0; mt < 4; ++mt)
                af[mt] = *(const shortx8*)(aBase + mt * 16 * DIM + kc + BK);
            #pragma unroll
            for (int nt = 0; nt < 4; ++nt) {
                int R = wn + nt * 16 + fr;
                bfr[nt] = *(const shortx8*)(Bs + R * BK + ((fq ^ ((R ^ (R >> 2)) & 3)) * 8));
            }
            #pragma unroll
            for (int mt = 0; mt < 4; ++mt)
                #pragma unroll
                for (int nt = 0; nt < 4; ++nt)
                    acc[mt][nt] = __builtin_amdgcn_mfma_f32_16x16x32_bf16(
                        af[mt], bfr[nt], acc[mt][nt], 0, 0, 0);
        }
    }

    // per-class 1/||w||: reduce sumsq across the k-chunk quad
    sq0 += __shfl_xor(sq0, 1); sq0 += __shfl_xor(sq0, 2);
    sq1 += __shfl_xor(sq1, 1); sq1 += __shfl_xor(sq1, 2);
    if (kq == 0) {
        invs[r0]      = rsqrtf(fmaxf(sq0, 1e-24f));
        invs[64 + r0] = rsqrtf(fmaxf(sq1, 1e-24f));
    }
    __syncthreads();

    // epilogue: cosine = acc * invn[col]; exp(64c - 64); reduce per row
    const float CLIPC = 0.99999950f;  // cos(0.001)
    float invn4[4];
    #pragma unroll
    for (int nt = 0; nt < 4; ++nt) invn4[nt] = invs[wn + nt * 16 + fr];
    int colbase = ctile * 128 + wn + fr;
    #pragma unroll
    for (int mt = 0; mt < 4; ++mt) {
        #pragma unroll
        for (int reg = 0; reg < 4; ++reg) {
            float s = 0.0f;
            #pragma unroll
            for (int nt = 0; nt < 4; ++nt) {
                int col = colbase + nt * 16;
                float c = acc[mt][nt][reg] * invn4[nt];
                c = fminf(fmaxf(c, -CLIPC), CLIPC);
                float term = __expf(64.0f * c - 64.0f);
                s += (col < NCLS) ? term : 0.0f;
            }
            s += __shfl_xor(s, 1); s += __shfl_xor(s, 2);
            s += __shfl_xor(s, 4); s += __shfl_xor(s, 8);
            if (fr == 0) atomicAdd(&red[wm + mt * 16 + fq * 4 + reg], s);
        }
    }
    __syncthreads();
    if (t < 128) atomicAdd(rowsum + mtile * 128 + t, red[t]);
}

// --- kernel 4: fused batch-stats + margin correction + log + mean ----------
__global__ __launch_bounds__(1024) void finalize_kernel(
        const float* __restrict__ rowsum, const float* __restrict__ coslab,
        const float* __restrict__ rownorm, float* __restrict__ out) {
    __shared__ float sd[1024];
    int t = threadIdx.x;
    float v = fminf(fmaxf(rownorm[t], 0.001f), 100.0f);   // safe_norms
    sd[t] = v; __syncthreads();
    for (int s = 512; s > 0; s >>= 1) { if (t < s) sd[t] += sd[t + s]; __syncthreads(); }
    float mean = sd[0] * (1.0f / 1024.0f);
    __syncthreads();
    float d = v - mean;
    sd[t] = d * d; __syncthreads();
    for (int s = 512; s > 0; s >>= 1) { if (t < s) sd[t] += sd[t + s]; __syncthreads(); }
    float stdv = sqrtf(sd[0] * (1.0f / 1023.0f));         // ddof=1
    float ms = d / (stdv + 0.001f) * 0.333f;
    ms = fminf(fmaxf(ms, -1.0f), 1.0f);
    float g_ang = -0.4f * ms;
    float g_add =  0.4f + 0.4f * ms;
    const float CLIPC = 0.99999950f;
    const float PI = 3.14159265358979323846f;
    float cl  = fminf(fmaxf(coslab[t], -1.0f), 1.0f);
    float cne = fminf(fmaxf(cl, -CLIPC), CLIPC);
    float logit_non = 64.0f * cne;                        // what the GEMM summed
    float theta = acosf(cl);
    float tm = fminf(fmaxf(theta + g_ang, 0.001f), PI - 0.001f);
    float logit_true = (__cosf(tm) - g_add) * 64.0f;
    float ssum = rowsum[t] - __expf(logit_non - 64.0f) + __expf(logit_true - 64.0f);
    float loss = logf(ssum) + 64.0f - logit_true;
    __syncthreads();
    sd[t] = loss; __syncthreads();
    for (int s = 512; s > 0; s >>= 1) { if (t < s) sd[t] += sd[t + s]; __syncthreads(); }
    if (t == 0) out[0] = sd[0] * (1.0f / 1024.0f);
}

extern "C" void kernel_launch(void* const* d_in, const int* in_sizes, int n_in,
                              void* d_out, int out_size, void* d_ws, size_t ws_size,
                              hipStream_t stream) {
    const float* x      = (const float*)d_in[0];
    const int*   labels = (const int*)d_in[1];
    const float* W      = (const float*)d_in[2];
    float* out = (float*)d_out;
    char* ws = (char*)d_ws;

    // workspace: normx 1 MB + small vectors (~1.06 MB total)
    unsigned short* normx = (unsigned short*)ws;
    float* rownorm = (float*)(ws + 1048576);
    float* rowsum  = rownorm + 1024;
    float* coslab  = rowsum + 1024;

    prep_x_kernel<<<NROWS / 4, 256, 0, stream>>>(x, normx, rownorm, rowsum);
    coslab_kernel<<<NROWS / 4, 256, 0, stream>>>(x, W, labels, coslab);
    gemm3_kernel<<<70 * 64, 256, 0, stream>>>(normx, W, rowsum);
    finalize_kernel<<<1, 1024, 0, stream>>>(rowsum, coslab, rownorm, out);
}

// Round 6
// 337.833 us; speedup vs baseline: 1.2262x; 1.2262x over previous
//
#include <hip/hip_runtime.h>
#include <hip/hip_bf16.h>
#include <stdint.h>

#define DIM 512
#define NROWS 1024
#define NCLS 70722
#define BK 32
#define BM 256
#define NCTILE 553     // ceil(70722/128)

typedef float  floatx4 __attribute__((ext_vector_type(4)));
typedef short  shortx8 __attribute__((ext_vector_type(8)));

__device__ __forceinline__ unsigned short f2bf(float f) {
    union { float f; unsigned int u; } v; v.f = f;
    unsigned int r = v.u + 0x7FFFu + ((v.u >> 16) & 1u);  // RNE
    return (unsigned short)(r >> 16);
}

__device__ __forceinline__ float wave_reduce_sum(float s) {
    #pragma unroll
    for (int m = 1; m < 64; m <<= 1) s += __shfl_xor(s, m);
    return s;
}

// --- kernel 1: fused per-row x norm + bf16 x + label-column cosine ---------
__global__ __launch_bounds__(256) void prep_x_kernel(
        const float* __restrict__ x, const float* __restrict__ W,
        const int* __restrict__ labels, unsigned short* __restrict__ normx,
        float* __restrict__ rownorm, float* __restrict__ coslab,
        float* __restrict__ rowsum) {
    int wv = threadIdx.x >> 6, lane = threadIdx.x & 63;
    if (threadIdx.x < 4) rowsum[blockIdx.x * 4 + threadIdx.x] = 0.0f;
    int row = blockIdx.x * 4 + wv;
    int lab = labels[row];
    const float4* xs = (const float4*)(x + row * DIM);
    const float4* ws = (const float4*)(W + (size_t)lab * DIM);
    float4 xa = xs[lane], xb = xs[lane + 64];
    float4 wa = ws[lane], wb = ws[lane + 64];
    float dxx = xa.x*xa.x + xa.y*xa.y + xa.z*xa.z + xa.w*xa.w
              + xb.x*xb.x + xb.y*xb.y + xb.z*xb.z + xb.w*xb.w;
    float dww = wa.x*wa.x + wa.y*wa.y + wa.z*wa.z + wa.w*wa.w
              + wb.x*wb.x + wb.y*wb.y + wb.z*wb.z + wb.w*wb.w;
    float dxw = xa.x*wa.x + xa.y*wa.y + xa.z*wa.z + xa.w*wa.w
              + xb.x*wb.x + xb.y*wb.y + xb.z*wb.z + xb.w*wb.w;
    dxx = wave_reduce_sum(dxx);
    dww = wave_reduce_sum(dww);
    dxw = wave_reduce_sum(dxw);
    float norm = sqrtf(dxx);
    float inv  = 1.0f / fmaxf(norm, 1e-12f);
    ushort4 o0; o0.x = f2bf(xa.x*inv); o0.y = f2bf(xa.y*inv); o0.z = f2bf(xa.z*inv); o0.w = f2bf(xa.w*inv);
    ushort4 o1; o1.x = f2bf(xb.x*inv); o1.y = f2bf(xb.y*inv); o1.z = f2bf(xb.z*inv); o1.w = f2bf(xb.w*inv);
    ((ushort4*)(normx + row * DIM))[lane]      = o0;
    ((ushort4*)(normx + row * DIM))[lane + 64] = o1;
    if (lane == 0) {
        rownorm[row] = norm;
        coslab[row]  = dxw / (fmaxf(norm, 1e-12f) * fmaxf(sqrtf(dww), 1e-12f));
    }
}

// --- kernel 2: normalized bf16 W (16 lanes/row, 4 rows/wave, 16 rows/block)
__global__ __launch_bounds__(256) void prep_w_conv_kernel(
        const float* __restrict__ W, unsigned short* __restrict__ Wn) {
    int wv = threadIdx.x >> 6, lane = threadIdx.x & 63;
    int sub = lane >> 4, l16 = lane & 15;
    int c = blockIdx.x * 16 + wv * 4 + sub;
    c = min(c, NCLS - 1);                       // dup-write of last row is benign
    const float4* src = (const float4*)(W + (size_t)c * DIM + l16 * 32);
    float4 v[8];
    #pragma unroll
    for (int i = 0; i < 8; ++i) v[i] = src[i];
    float ss = 0.0f;
    #pragma unroll
    for (int i = 0; i < 8; ++i)
        ss += v[i].x*v[i].x + v[i].y*v[i].y + v[i].z*v[i].z + v[i].w*v[i].w;
    ss += __shfl_xor(ss, 1); ss += __shfl_xor(ss, 2);
    ss += __shfl_xor(ss, 4); ss += __shfl_xor(ss, 8);
    float inv = 1.0f / fmaxf(sqrtf(ss), 1e-12f);
    uint4* dst = (uint4*)(Wn + (size_t)c * DIM + l16 * 32);
    #pragma unroll
    for (int i = 0; i < 4; ++i) {
        float4 a = v[2*i], b = v[2*i+1];
        union { unsigned short u[8]; uint4 q; } pk;
        pk.u[0]=f2bf(a.x*inv); pk.u[1]=f2bf(a.y*inv); pk.u[2]=f2bf(a.z*inv); pk.u[3]=f2bf(a.w*inv);
        pk.u[4]=f2bf(b.x*inv); pk.u[5]=f2bf(b.y*inv); pk.u[6]=f2bf(b.z*inv); pk.u[7]=f2bf(b.w*inv);
        dst[i] = pk.q;
    }
}

// --- kernel 3: 256x128 bf16 GEMM, swizzled global_load_lds, fused sumexp ---
// Swizzle: LDS slot (row r, chunk s) holds source k-chunk s^g(r), g=(r^(r>>2))&3.
// Fragment reads at slot fq^g(fr) land exactly 2 lanes/bank (free).
// XCD swizzle: blocks with same b%8 share ctile%8 -> same XCD L2 reuse of B.
__global__ __launch_bounds__(256, 2) void gemm4_kernel(
        const unsigned short* __restrict__ normx, const unsigned short* __restrict__ Wn,
        float* __restrict__ rowsum) {
    __shared__ unsigned short As[BM * BK];    // 16 KB
    __shared__ unsigned short Bs[128 * BK];   // 8 KB
    __shared__ float red[BM];
    int b = blockIdx.x;
    int ctile = (b >> 5) * 8 + (b & 7);
    int mtile = (b >> 3) & 3;
    if (ctile >= NCTILE) return;              // whole block exits together
    int t = threadIdx.x, lane = t & 63, wv = t >> 6;
    red[t] = 0.0f;

    // staging map: lane covers row-in-group sr, source chunk (lane&3)^g(sr)
    int sr = lane >> 2;
    int gs = (sr ^ (sr >> 2)) & 3;
    int skoff = ((lane & 3) ^ gs) * 8;
    const unsigned short* aG = normx + (size_t)(mtile * BM + wv * 16 + sr) * DIM + skoff;
    int c0 = min(ctile * 128 + wv * 16 + sr,      NCLS - 1);
    int c1 = min(ctile * 128 + 64 + wv * 16 + sr, NCLS - 1);
    const unsigned short* bG0 = Wn + (size_t)c0 * DIM + skoff;
    const unsigned short* bG1 = Wn + (size_t)c1 * DIM + skoff;
    unsigned short* aL = As + wv * 16 * BK;   // wave-uniform LDS bases
    unsigned short* bL = Bs + wv * 16 * BK;

    // fragment map: waves 2x2 over (256 m, 128 n); each wave 128x64
    int wi = wv >> 1, wj = wv & 1;
    int fr = lane & 15, fq = lane >> 4;
    int slot = (fq ^ ((fr ^ (fr >> 2)) & 3)) * 8;

    floatx4 acc[8][4] = {};

    for (int kc = 0; kc < DIM; kc += BK) {
        __syncthreads();   // prior fragment reads done before overwrite
        #pragma unroll
        for (int jj = 0; jj < 4; ++jj)
            __builtin_amdgcn_global_load_lds(
                (const __attribute__((address_space(1))) unsigned int*)(aG + (size_t)jj * 64 * DIM + kc),
                (__attribute__((address_space(3))) unsigned int*)(aL + jj * 64 * BK), 16, 0, 0);
        __builtin_amdgcn_global_load_lds(
            (const __attribute__((address_space(1))) unsigned int*)(bG0 + kc),
            (__attribute__((address_space(3))) unsigned int*)(bL), 16, 0, 0);
        __builtin_amdgcn_global_load_lds(
            (const __attribute__((address_space(1))) unsigned int*)(bG1 + kc),
            (__attribute__((address_space(3))) unsigned int*)(bL + 64 * BK), 16, 0, 0);
        __syncthreads();   // drains vmcnt -> LDS ready
        shortx8 af[8], bfr[4];
        #pragma unroll
        for (int mt = 0; mt < 8; ++mt)
            af[mt] = *(const shortx8*)(As + (wi * 128 + mt * 16 + fr) * BK + slot);
        #pragma unroll
        for (int nt = 0; nt < 4; ++nt)
            bfr[nt] = *(const shortx8*)(Bs + (wj * 64 + nt * 16 + fr) * BK + slot);
        #pragma unroll
        for (int mt = 0; mt < 8; ++mt)
            #pragma unroll
            for (int nt = 0; nt < 4; ++nt)
                acc[mt][nt] = __builtin_amdgcn_mfma_f32_16x16x32_bf16(
                    af[mt], bfr[nt], acc[mt][nt], 0, 0, 0);
    }

    // epilogue: exp(64c - 64), reduce per row
    const float CLIPC = 0.99999950f;  // cos(0.001)
    int colbase = ctile * 128 + wj * 64 + fr;
    #pragma unroll
    for (int mt = 0; mt < 8; ++mt) {
        #pragma unroll
        for (int reg = 0; reg < 4; ++reg) {
            float s = 0.0f;
            #pragma unroll
            for (int nt = 0; nt < 4; ++nt) {
                int col = colbase + nt * 16;
                float c = acc[mt][nt][reg];
                c = fminf(fmaxf(c, -CLIPC), CLIPC);
                float term = __expf(64.0f * c - 64.0f);
                s += (col < NCLS) ? term : 0.0f;
            }
            s += __shfl_xor(s, 1); s += __shfl_xor(s, 2);
            s += __shfl_xor(s, 4); s += __shfl_xor(s, 8);
            if (fr == 0) atomicAdd(&red[wi * 128 + mt * 16 + fq * 4 + reg], s);
        }
    }
    __syncthreads();
    atomicAdd(rowsum + mtile * BM + t, red[t]);
}

// --- kernel 4: fused batch-stats + margin correction + log + mean ----------
__global__ __launch_bounds__(1024) void finalize_kernel(
        const float* __restrict__ rowsum, const float* __restrict__ coslab,
        const float* __restrict__ rownorm, float* __restrict__ out) {
    __shared__ float sd[1024];
    int t = threadIdx.x;
    float v = fminf(fmaxf(rownorm[t], 0.001f), 100.0f);   // safe_norms
    sd[t] = v; __syncthreads();
    for (int s = 512; s > 0; s >>= 1) { if (t < s) sd[t] += sd[t + s]; __syncthreads(); }
    float mean = sd[0] * (1.0f / 1024.0f);
    __syncthreads();
    float d = v - mean;
    sd[t] = d * d; __syncthreads();
    for (int s = 512; s > 0; s >>= 1) { if (t < s) sd[t] += sd[t + s]; __syncthreads(); }
    float stdv = sqrtf(sd[0] * (1.0f / 1023.0f));         // ddof=1
    float ms = d / (stdv + 0.001f) * 0.333f;
    ms = fminf(fmaxf(ms, -1.0f), 1.0f);
    float g_ang = -0.4f * ms;
    float g_add =  0.4f + 0.4f * ms;
    const float CLIPC = 0.99999950f;
    const float PI = 3.14159265358979323846f;
    float cl  = fminf(fmaxf(coslab[t], -1.0f), 1.0f);
    float cne = fminf(fmaxf(cl, -CLIPC), CLIPC);
    float logit_non = 64.0f * cne;                        // what the GEMM summed
    float theta = acosf(cl);
    float tm = fminf(fmaxf(theta + g_ang, 0.001f), PI - 0.001f);
    float logit_true = (__cosf(tm) - g_add) * 64.0f;
    float ssum = rowsum[t] - __expf(logit_non - 64.0f) + __expf(logit_true - 64.0f);
    float loss = logf(ssum) + 64.0f - logit_true;
    __syncthreads();
    sd[t] = loss; __syncthreads();
    for (int s = 512; s > 0; s >>= 1) { if (t < s) sd[t] += sd[t + s]; __syncthreads(); }
    if (t == 0) out[0] = sd[0] * (1.0f / 1024.0f);
}

extern "C" void kernel_launch(void* const* d_in, const int* in_sizes, int n_in,
                              void* d_out, int out_size, void* d_ws, size_t ws_size,
                              hipStream_t stream) {
    const float* x      = (const float*)d_in[0];
    const int*   labels = (const int*)d_in[1];
    const float* W      = (const float*)d_in[2];
    float* out = (float*)d_out;
    char* ws = (char*)d_ws;

    // workspace layout (~73.5 MB; harness provided >=73.7 MB in rounds 2-3)
    const size_t SZ_WN    = 72419328;     // 70722*512*2
    const size_t SZ_NORMX = 1048576;      // 1024*512*2
    unsigned short* Wn    = (unsigned short*)ws;
    unsigned short* normx = (unsigned short*)(ws + SZ_WN);
    float* rownorm = (float*)(ws + SZ_WN + SZ_NORMX);
    float* rowsum  = rownorm + 1024;
    float* coslab  = rowsum + 1024;

    prep_x_kernel<<<NROWS / 4, 256, 0, stream>>>(x, W, labels, normx, rownorm, coslab, rowsum);
    prep_w_conv_kernel<<<(NCLS + 15) / 16, 256, 0, stream>>>(W, Wn);
    gemm4_kernel<<<70 * 32, 256, 0, stream>>>(normx, Wn, rowsum);
    finalize_kernel<<<1, 1024, 0, stream>>>(rowsum, coslab, rownorm, out);
}

// Round 7
// 315.909 us; speedup vs baseline: 1.3113x; 1.0694x over previous
//
#include <hip/hip_runtime.h>
#include <hip/hip_bf16.h>
#include <stdint.h>

#define DIM 512
#define NROWS 1024
#define NCLS 70722
#define NCTILE 553     // ceil(70722/128)

typedef float floatx4 __attribute__((ext_vector_type(4)));

// pack 4 floats -> 4 OCP e4m3 bytes (HW cvt, RNE+sat)
__device__ __forceinline__ unsigned pk4_fp8(float a, float b, float c, float d) {
    unsigned v = 0;
    v = __builtin_amdgcn_cvt_pk_fp8_f32(a, b, v, false);  // low 16 bits
    v = __builtin_amdgcn_cvt_pk_fp8_f32(c, d, v, true);   // high 16 bits
    return v;
}

__device__ __forceinline__ float wave_reduce_sum(float s) {
    #pragma unroll
    for (int m = 1; m < 64; m <<= 1) s += __shfl_xor(s, m);
    return s;
}

// --- kernel 1: fused prep ---------------------------------------------------
// blocks [0,256):    x rows -> fp8(16*x/||x||), rownorm, fp32 label cosine, rowsum=0
// blocks [256,4677): W rows -> fp8(16*w/||w||)
__global__ __launch_bounds__(256) void prep_kernel(
        const float* __restrict__ x, const float* __restrict__ W,
        const int* __restrict__ labels,
        uint8_t* __restrict__ An, uint8_t* __restrict__ Wn8,
        float* __restrict__ rownorm, float* __restrict__ coslab,
        float* __restrict__ rowsum) {
    int b = blockIdx.x;
    int wv = threadIdx.x >> 6, lane = threadIdx.x & 63;
    if (b < NROWS / 4) {
        if (threadIdx.x < 4) rowsum[b * 4 + threadIdx.x] = 0.0f;
        int row = b * 4 + wv;
        int lab = labels[row];
        // lane covers 8 contiguous elements
        const float4* xs = (const float4*)(x + (size_t)row * DIM);
        const float4* ws = (const float4*)(W + (size_t)lab * DIM);
        float4 xa = xs[lane * 2], xb = xs[lane * 2 + 1];
        float4 wa = ws[lane * 2], wb = ws[lane * 2 + 1];
        float dxx = xa.x*xa.x + xa.y*xa.y + xa.z*xa.z + xa.w*xa.w
                  + xb.x*xb.x + xb.y*xb.y + xb.z*xb.z + xb.w*xb.w;
        float dww = wa.x*wa.x + wa.y*wa.y + wa.z*wa.z + wa.w*wa.w
                  + wb.x*wb.x + wb.y*wb.y + wb.z*wb.z + wb.w*wb.w;
        float dxw = xa.x*wa.x + xa.y*wa.y + xa.z*wa.z + xa.w*wa.w
                  + xb.x*wb.x + xb.y*wb.y + xb.z*wb.z + xb.w*wb.w;
        dxx = wave_reduce_sum(dxx);
        dww = wave_reduce_sum(dww);
        dxw = wave_reduce_sum(dxw);
        float norm = sqrtf(dxx);
        float s16 = 16.0f / fmaxf(norm, 1e-12f);
        uint2 p;
        p.x = pk4_fp8(xa.x*s16, xa.y*s16, xa.z*s16, xa.w*s16);
        p.y = pk4_fp8(xb.x*s16, xb.y*s16, xb.z*s16, xb.w*s16);
        *(uint2*)(An + (size_t)row * DIM + lane * 8) = p;
        if (lane == 0) {
            rownorm[row] = norm;
            coslab[row]  = dxw / (fmaxf(norm, 1e-12f) * fmaxf(sqrtf(dww), 1e-12f));
        }
    } else {
        int c = (b - NROWS / 4) * 16 + wv * 4 + (lane >> 4);
        c = min(c, NCLS - 1);                     // dup writes benign
        int l16 = lane & 15;
        const float4* src = (const float4*)(W + (size_t)c * DIM + l16 * 32);
        float4 v[8];
        #pragma unroll
        for (int i = 0; i < 8; ++i) v[i] = src[i];
        float ss = 0.0f;
        #pragma unroll
        for (int i = 0; i < 8; ++i)
            ss += v[i].x*v[i].x + v[i].y*v[i].y + v[i].z*v[i].z + v[i].w*v[i].w;
        ss += __shfl_xor(ss, 1); ss += __shfl_xor(ss, 2);
        ss += __shfl_xor(ss, 4); ss += __shfl_xor(ss, 8);
        float s16 = 16.0f / fmaxf(sqrtf(ss), 1e-12f);
        uint4 q0, q1;
        q0.x = pk4_fp8(v[0].x*s16, v[0].y*s16, v[0].z*s16, v[0].w*s16);
        q0.y = pk4_fp8(v[1].x*s16, v[1].y*s16, v[1].z*s16, v[1].w*s16);
        q0.z = pk4_fp8(v[2].x*s16, v[2].y*s16, v[2].z*s16, v[2].w*s16);
        q0.w = pk4_fp8(v[3].x*s16, v[3].y*s16, v[3].z*s16, v[3].w*s16);
        q1.x = pk4_fp8(v[4].x*s16, v[4].y*s16, v[4].z*s16, v[4].w*s16);
        q1.y = pk4_fp8(v[5].x*s16, v[5].y*s16, v[5].z*s16, v[5].w*s16);
        q1.z = pk4_fp8(v[6].x*s16, v[6].y*s16, v[6].z*s16, v[6].w*s16);
        q1.w = pk4_fp8(v[7].x*s16, v[7].y*s16, v[7].z*s16, v[7].w*s16);
        uint4* dst = (uint4*)(Wn8 + (size_t)c * DIM + l16 * 32);
        dst[0] = q0;
        dst[1] = q1;
    }
}

// --- kernel 2: fp8 128x128 GEMM, BK=64, swizzled global_load_lds + sumexp ---
// LDS row = 64 fp8 = 4 x 16B chunks; chunk q of row r holds source chunk
// q^(r&3) (swizzle legal: global_load_lds source addr is per-lane, dest is
// wave-uniform + lane*16). acc * 2^-8 = cosine (inputs pre-scaled by 16).
// XCD swizzle: blocks sharing b%8 share ctile%8 -> same XCD L2 reuse of B.
__global__ __launch_bounds__(256) void gemm5_kernel(
        const uint8_t* __restrict__ An, const uint8_t* __restrict__ Wn8,
        float* __restrict__ rowsum) {
    __shared__ uint8_t As[128 * 64];   // 8 KB
    __shared__ uint8_t Bs[128 * 64];   // 8 KB
    __shared__ float red[128];
    int b = blockIdx.x;
    int ctile = (b >> 6) * 8 + (b & 7);
    int mtile = (b >> 3) & 7;
    if (ctile >= NCTILE) return;
    int t = threadIdx.x, lane = t & 63, wv = t >> 6;
    if (t < 128) red[t] = 0.0f;

    // staging: issue covers 16 rows x 64 B; lane -> row sr=lane>>2, chunk lane&3
    int sr = lane >> 2;
    int ck = (((lane & 3) ^ (sr & 3)) * 16);  // swizzled source chunk offset
    const uint8_t* aG = An + (size_t)(mtile * 128 + wv * 16 + sr) * DIM + ck;
    int c0 = min(ctile * 128 + wv * 16 + sr,      NCLS - 1);
    int c1 = min(ctile * 128 + 64 + wv * 16 + sr, NCLS - 1);
    const uint8_t* bG0 = Wn8 + (size_t)c0 * DIM + ck;
    const uint8_t* bG1 = Wn8 + (size_t)c1 * DIM + ck;
    uint8_t* aL = As + wv * 16 * 64;          // wave-uniform LDS bases
    uint8_t* bL = Bs + wv * 16 * 64;

    int wm = (wv >> 1) * 64, wn = (wv & 1) * 64;
    int fr = lane & 15, fq = lane >> 4;
    int fh = fq >> 1, fl = (fq & 1) * 8;      // chunk-half / 8B sub-slot

    floatx4 acc[4][4] = {};

    for (int kc = 0; kc < DIM; kc += 64) {
        __syncthreads();   // prior fragment reads done before overwrite
        __builtin_amdgcn_global_load_lds(
            (const __attribute__((address_space(1))) unsigned int*)(aG + kc),
            (__attribute__((address_space(3))) unsigned int*)(aL), 16, 0, 0);
        __builtin_amdgcn_global_load_lds(
            (const __attribute__((address_space(1))) unsigned int*)(aG + (size_t)64 * DIM + kc),
            (__attribute__((address_space(3))) unsigned int*)(aL + 64 * 64), 16, 0, 0);
        __builtin_amdgcn_global_load_lds(
            (const __attribute__((address_space(1))) unsigned int*)(bG0 + kc),
            (__attribute__((address_space(3))) unsigned int*)(bL), 16, 0, 0);
        __builtin_amdgcn_global_load_lds(
            (const __attribute__((address_space(1))) unsigned int*)(bG1 + kc),
            (__attribute__((address_space(3))) unsigned int*)(bL + 64 * 64), 16, 0, 0);
        __syncthreads();   // drains vmcnt -> LDS ready
        long af[2][4], bf[2][4];
        #pragma unroll
        for (int mt = 0; mt < 4; ++mt) {
            int R = wm + mt * 16 + fr;
            const uint8_t* rp = As + R * 64;
            #pragma unroll
            for (int s = 0; s < 2; ++s) {
                int csrc = s * 2 + fh;          // source 16B chunk for k=s*32+fq*8
                af[s][mt] = *(const long*)(rp + ((csrc ^ (R & 3)) * 16) + fl);
            }
        }
        #pragma unroll
        for (int nt = 0; nt < 4; ++nt) {
            int R = wn + nt * 16 + fr;
            const uint8_t* rp = Bs + R * 64;
            #pragma unroll
            for (int s = 0; s < 2; ++s) {
                int csrc = s * 2 + fh;
                bf[s][nt] = *(const long*)(rp + ((csrc ^ (R & 3)) * 16) + fl);
            }
        }
        #pragma unroll
        for (int s = 0; s < 2; ++s)
            #pragma unroll
            for (int mt = 0; mt < 4; ++mt)
                #pragma unroll
                for (int nt = 0; nt < 4; ++nt)
                    acc[mt][nt] = __builtin_amdgcn_mfma_f32_16x16x32_fp8_fp8(
                        af[s][mt], bf[s][nt], acc[mt][nt], 0, 0, 0);
    }

    // epilogue: cosine = acc/256; exp(64c - 64); reduce per row
    const float CLIPC = 0.99999950f;  // cos(0.001)
    const float ISCL  = 1.0f / 256.0f;
    int colbase = ctile * 128 + wn + fr;
    #pragma unroll
    for (int mt = 0; mt < 4; ++mt) {
        #pragma unroll
        for (int reg = 0; reg < 4; ++reg) {
            float s = 0.0f;
            #pragma unroll
            for (int nt = 0; nt < 4; ++nt) {
                int col = colbase + nt * 16;
                float c = acc[mt][nt][reg] * ISCL;
                c = fminf(fmaxf(c, -CLIPC), CLIPC);
                float term = __expf(64.0f * c - 64.0f);
                s += (col < NCLS) ? term : 0.0f;
            }
            s += __shfl_xor(s, 1); s += __shfl_xor(s, 2);
            s += __shfl_xor(s, 4); s += __shfl_xor(s, 8);
            if (fr == 0) atomicAdd(&red[wm + mt * 16 + fq * 4 + reg], s);
        }
    }
    __syncthreads();
    if (t < 128) atomicAdd(rowsum + mtile * 128 + t, red[t]);
}

// --- kernel 3: fused batch-stats + margin correction + log + mean ----------
__global__ __launch_bounds__(1024) void finalize_kernel(
        const float* __restrict__ rowsum, const float* __restrict__ coslab,
        const float* __restrict__ rownorm, float* __restrict__ out) {
    __shared__ float sd[1024];
    int t = threadIdx.x;
    float v = fminf(fmaxf(rownorm[t], 0.001f), 100.0f);   // safe_norms
    sd[t] = v; __syncthreads();
    for (int s = 512; s > 0; s >>= 1) { if (t < s) sd[t] += sd[t + s]; __syncthreads(); }
    float mean = sd[0] * (1.0f / 1024.0f);
    __syncthreads();
    float d = v - mean;
    sd[t] = d * d; __syncthreads();
    for (int s = 512; s > 0; s >>= 1) { if (t < s) sd[t] += sd[t + s]; __syncthreads(); }
    float stdv = sqrtf(sd[0] * (1.0f / 1023.0f));         // ddof=1
    float ms = d / (stdv + 0.001f) * 0.333f;
    ms = fminf(fmaxf(ms, -1.0f), 1.0f);
    float g_ang = -0.4f * ms;
    float g_add =  0.4f + 0.4f * ms;
    const float CLIPC = 0.99999950f;
    const float PI = 3.14159265358979323846f;
    float cl  = fminf(fmaxf(coslab[t], -1.0f), 1.0f);
    float cne = fminf(fmaxf(cl, -CLIPC), CLIPC);
    float logit_non = 64.0f * cne;                        // ~ what the GEMM summed
    float theta = acosf(cl);
    float tm = fminf(fmaxf(theta + g_ang, 0.001f), PI - 0.001f);
    float logit_true = (__cosf(tm) - g_add) * 64.0f;
    float ssum = rowsum[t] - __expf(logit_non - 64.0f) + __expf(logit_true - 64.0f);
    float loss = logf(ssum) + 64.0f - logit_true;
    __syncthreads();
    sd[t] = loss; __syncthreads();
    for (int s = 512; s > 0; s >>= 1) { if (t < s) sd[t] += sd[t + s]; __syncthreads(); }
    if (t == 0) out[0] = sd[0] * (1.0f / 1024.0f);
}

extern "C" void kernel_launch(void* const* d_in, const int* in_sizes, int n_in,
                              void* d_out, int out_size, void* d_ws, size_t ws_size,
                              hipStream_t stream) {
    const float* x      = (const float*)d_in[0];
    const int*   labels = (const int*)d_in[1];
    const float* W      = (const float*)d_in[2];
    float* out = (float*)d_out;
    char* ws = (char*)d_ws;

    // workspace layout (~36.8 MB)
    const size_t SZ_WN8 = 36212736;   // 70722*512 fp8, 4K-aligned pad
    const size_t SZ_AN  = 524288;     // 1024*512 fp8
    uint8_t* Wn8 = (uint8_t*)ws;
    uint8_t* An  = (uint8_t*)(ws + SZ_WN8);
    float* rownorm = (float*)(ws + SZ_WN8 + SZ_AN);
    float* rowsum  = rownorm + 1024;
    float* coslab  = rowsum + 1024;

    int wblocks = (NCLS + 15) / 16;
    prep_kernel<<<NROWS / 4 + wblocks, 256, 0, stream>>>(
        x, W, labels, An, Wn8, rownorm, coslab, rowsum);
    gemm5_kernel<<<70 * 64, 256, 0, stream>>>(An, Wn8, rowsum);
    finalize_kernel<<<1, 1024, 0, stream>>>(rowsum, coslab, rownorm, out);
}